// Round 4
// baseline (250.637 us; speedup 1.0000x reference)
//
#include <hip/hip_runtime.h>
#include <hip/hip_bf16.h>

// MinGRU forward: z=sigmoid(xWz^T), h~=xWh^T, a=1-z+1e-8, b=z*h~, scan h=a*h+b.
// B=4 T=4096 D=1024.
// R7: gemm wait-cadence fix. R6 issued stages per-phase and waited 2-3 phases
// later -- B(2t+2) had only 2 phases of flight (~latency edge of L2/L3
// global_load_lds), so P2/P4 stalled like a drain. Now ALL 8 stage items for
// kblks {2t+2, 2t+3} issue at P1 (order: A0,B0,A1,B1), waits move to the
// last-legal points: vmcnt(8) at P2 (retires {A,B}(2t+1), 5 phases after
// issue), vmcnt(4) at P4 (retires {A,B}(2t+2), 3 phases). WAR on overwritten
// slots protected by post-MFMA barriers of the iteration that last read them.
// Everything else (convert, epilogue, pass2, pass3) byte-identical to R6 for
// clean attribution.

typedef __bf16 bf16x8 __attribute__((ext_vector_type(8)));
typedef __bf16 bf16x4 __attribute__((ext_vector_type(4)));
typedef float  f32x4  __attribute__((ext_vector_type(4)));

#define BSZ 4
#define TSZ 4096
#define DSZ 1024
#define MSZ (BSZ*TSZ)      // 16384 rows
#define NSZ 2048           // concat-N (z|h interleaved by 16-col groups)
#define CH  16             // scan chunk length
#define NC  (TSZ/CH)       // 256 chunks per sequence

#define BAR()  asm volatile("s_barrier" ::: "memory")
#define VMW(n) asm volatile("s_waitcnt vmcnt(" #n ")" ::: "memory")

__device__ __forceinline__ void gload_lds16(const __bf16* g, __bf16* l) {
  __builtin_amdgcn_global_load_lds(
      (const __attribute__((address_space(1))) void*)g,
      (__attribute__((address_space(3))) void*)l, 16, 0, 0);
}

// ---------------- conversion: fp32 row-major -> bf16 fragment-tiled ----------------
// tiled layout per 128-row block: [kblk:32][i:8][l:64][j:8] where
//   row = i*16 + (l&15), k = kblk*32 + (l>>4)*8 + j
// W_cat row g*16+s: g even -> Wz row (g>>1)*16+s, g odd -> Wh row (g>>1)*16+s.
__global__ void convert_tile_kernel(const float* __restrict__ X,
                                    const float* __restrict__ Wz,
                                    const float* __restrict__ Wh,
                                    __bf16* __restrict__ Xc,
                                    __bf16* __restrict__ Wc)
{
  const int bx = blockIdx.x;
  const float* src; __bf16* dst; int gid; int row;
  if (bx < 8192) {
    gid = bx*256 + threadIdx.x;
    const int l = gid & 63, i = (gid >> 6) & 7, rblk = gid >> 14;
    row = rblk*128 + i*16 + (l & 15);
    src = X; dst = Xc;
  } else {
    gid = (bx - 8192)*256 + threadIdx.x;     // over 2048x1024/8 elems
    const int l = gid & 63, i = (gid >> 6) & 7, rblk = gid >> 14;  // rblk 0..15
    const int g = rblk*8 + i;                // 16-row group of W_cat, 0..127
    row = (g >> 1)*16 + (l & 15);
    src = (g & 1) ? Wh : Wz; dst = Wc;
  }
  const int l    = gid & 63;
  const int kblk = (gid >> 9) & 31;
  const int col  = kblk*32 + (l >> 4)*8;
  const float* g = src + (size_t)row*DSZ + col;
  float4 v0 = *(const float4*)g;
  float4 v1 = *(const float4*)(g + 4);
  bf16x8 p;
  p[0]=(__bf16)v0.x; p[1]=(__bf16)v0.y; p[2]=(__bf16)v0.z; p[3]=(__bf16)v0.w;
  p[4]=(__bf16)v1.x; p[5]=(__bf16)v1.y; p[6]=(__bf16)v1.z; p[7]=(__bf16)v1.w;
  *(bf16x8*)(dst + (size_t)gid*8) = p;
}

// ---------------- GEMM (256x256 tile, 4-phase counted-vmcnt) + gate epilogue ----
// 512 threads = 8 waves (2M x 4N), per-wave 128x64 output, acc[8][4] f32x4.
// K = 1024 = 16 iterations x 2 kblks (BK=32 each).
// Iteration t computes kblks {2t,2t+1} from slot pair (t&1), stages {2t+2,
// 2t+3} into the other pair -- ALL 8 items issued at P1 (A0,B0,A1,B1 order).
// Waits: vmcnt(8)@P2 retires {A,B}(2t+1) (cur slot1, 5 phases after issue);
// vmcnt(4)@P4 retires {A,B}(2t+2) (next P1's slot, 3 phases after issue).
// Invariant: each iteration starts with exactly 4 items outstanding
// ({A,B}(2t+1)); prologue establishes it via vmcnt(4). WAR on slot overwrite:
// slot 2t+3 === slot 2t-1, last ds_read in P3/P4(t-1); those reads complete
// before their own MFMAs (compiler lgkm waits) and the post-MFMA barrier of
// P4(t-1) precedes P1(t)'s stage issues.
__global__ __launch_bounds__(512, 2) void gemm_gate_kernel(
    const __bf16* __restrict__ Xc, const __bf16* __restrict__ Wc,
    const float* __restrict__ bz, const float* __restrict__ bh,
    __bf16* __restrict__ a_ws, float* __restrict__ b_out,
    float* __restrict__ Aprod, float* __restrict__ Bcomp)
{
  // [buf:2][kt:2][half:2][4096 elems] each -> 32768 elems = 64KB per matrix
  __shared__ __align__(16) __bf16 As[32768];
  __shared__ __align__(16) __bf16 Bs[32768];

  const int tid  = threadIdx.x;
  const int lane = tid & 63;
  const int w    = tid >> 6;           // 0..7
  const int wr   = w >> 2;             // 0..1 (M half)
  const int wc   = w & 3;              // 0..3 (N quarter)
  const int lr   = lane & 15;
  const int q    = lane >> 4;

  // XCD-chunked swizzle: 512 wgs, xcd=bid&7 owns contiguous chunk of 64.
  const int bid = blockIdx.x;
  const int wg  = (bid & 7)*64 + (bid >> 3);
  const int bx  = wg >> 3;             // 0..63 (M tiles of 256)
  const int by  = wg & 7;              // 0..7  (N tiles of 256)

  // staging addresses
  const int    lgo   = tid * 8;                        // global elem off in 4096-unit
  const int    llo   = (tid >> 6) * 512;               // wave-uniform LDS elem off
  const size_t xbase = (size_t)bx * 262144 + lgo;
  const size_t wbase = (size_t)by * 262144 + lgo;
  // ds_read bases
  const int ard   = wr*4096 + lane*8;                  // + kt*8192(buf) + m*512
  const int bbase = (wc >> 1)*4096 + (wc & 1)*2048 + lane*8;  // + j*512

  f32x4 acc[8][4] = {};
  bf16x8 a4[4], b4[4];

  // prologue: stage kblks 0,1 (8 items; first 4 = kblk0 A+B)
  #pragma unroll
  for (int h = 0; h < 2; ++h) gload_lds16(Xc + xbase + h*131072 + 0*4096, As + 0*8192 + h*4096 + llo);
  #pragma unroll
  for (int h = 0; h < 2; ++h) gload_lds16(Wc + wbase + h*131072 + 0*4096, Bs + 0*8192 + h*4096 + llo);
  #pragma unroll
  for (int h = 0; h < 2; ++h) gload_lds16(Xc + xbase + h*131072 + 1*4096, As + 1*8192 + h*4096 + llo);
  #pragma unroll
  for (int h = 0; h < 2; ++h) gload_lds16(Wc + wbase + h*131072 + 1*4096, Bs + 1*8192 + h*4096 + llo);
  VMW(4);   // kblk0 complete; {A,B}(1) stay outstanding (4) -- loop invariant
  BAR();

  for (int t = 0; t < 16; ++t) {
    const int cur = t & 1, nxt = cur ^ 1;
    const int cb0 = (cur*2 + 0)*8192;   // LDS elem base, kt=0
    const int cb1 = (cur*2 + 1)*8192;   // kt=1
    const int nb0 = (nxt*2 + 0)*8192;
    const int nb1 = (nxt*2 + 1)*8192;
    const size_t g0 = (size_t)(2*t + 2) * 4096;   // next A/B kblk offsets
    const size_t g1 = (size_t)(2*t + 3) * 4096;

    // ---- P1: kblk 2t, m0-3 x j0-3; issue ALL 8 stage items ----
    #pragma unroll
    for (int m = 0; m < 4; ++m) a4[m] = *(const bf16x8*)(As + cb0 + ard + m*512);
    #pragma unroll
    for (int j = 0; j < 4; ++j) b4[j] = *(const bf16x8*)(Bs + cb0 + bbase + j*512);
    if (t < 15) {
      #pragma unroll
      for (int h = 0; h < 2; ++h) gload_lds16(Xc + xbase + h*131072 + g0, As + nb0 + h*4096 + llo);
      #pragma unroll
      for (int h = 0; h < 2; ++h) gload_lds16(Wc + wbase + h*131072 + g0, Bs + nb0 + h*4096 + llo);
      #pragma unroll
      for (int h = 0; h < 2; ++h) gload_lds16(Xc + xbase + h*131072 + g1, As + nb1 + h*4096 + llo);
      #pragma unroll
      for (int h = 0; h < 2; ++h) gload_lds16(Wc + wbase + h*131072 + g1, Bs + nb1 + h*4096 + llo);
    }
    BAR();
    __builtin_amdgcn_s_setprio(1);
    #pragma unroll
    for (int j = 0; j < 4; ++j)
      #pragma unroll
      for (int m = 0; m < 4; ++m)
        acc[m][j] = __builtin_amdgcn_mfma_f32_16x16x32_bf16(a4[m], b4[j], acc[m][j], 0, 0, 0);
    __builtin_amdgcn_s_setprio(0);
    BAR();

    // ---- P2: kblk 2t, m4-7 x j0-3 (b4 reused) ----
    #pragma unroll
    for (int m = 0; m < 4; ++m) a4[m] = *(const bf16x8*)(As + cb0 + ard + (4+m)*512);
    if (t < 15) {
      VMW(8);   // retires {A,B}(2t+1): cur slot1 ready for P3 (5-phase flight)
    } else {
      VMW(0);   // t=15: only {A,B}(31) outstanding; drain for P3/P4
    }
    BAR();
    __builtin_amdgcn_s_setprio(1);
    #pragma unroll
    for (int j = 0; j < 4; ++j)
      #pragma unroll
      for (int m = 0; m < 4; ++m)
        acc[4+m][j] = __builtin_amdgcn_mfma_f32_16x16x32_bf16(a4[m], b4[j], acc[4+m][j], 0, 0, 0);
    __builtin_amdgcn_s_setprio(0);
    BAR();

    // ---- P3: kblk 2t+1, m0-3 x j0-3 ----
    #pragma unroll
    for (int m = 0; m < 4; ++m) a4[m] = *(const bf16x8*)(As + cb1 + ard + m*512);
    #pragma unroll
    for (int j = 0; j < 4; ++j) b4[j] = *(const bf16x8*)(Bs + cb1 + bbase + j*512);
    BAR();
    __builtin_amdgcn_s_setprio(1);
    #pragma unroll
    for (int j = 0; j < 4; ++j)
      #pragma unroll
      for (int m = 0; m < 4; ++m)
        acc[m][j] = __builtin_amdgcn_mfma_f32_16x16x32_bf16(a4[m], b4[j], acc[m][j], 0, 0, 0);
    __builtin_amdgcn_s_setprio(0);
    BAR();

    // ---- P4: kblk 2t+1, m4-7 x j0-3 ----
    #pragma unroll
    for (int m = 0; m < 4; ++m) a4[m] = *(const bf16x8*)(As + cb1 + ard + (4+m)*512);
    if (t < 15) {
      VMW(4);   // retires {A,B}(2t+2): next P1's slot (3-phase flight)
    }
    BAR();
    __builtin_amdgcn_s_setprio(1);
    #pragma unroll
    for (int j = 0; j < 4; ++j)
      #pragma unroll
      for (int m = 0; m < 4; ++m)
        acc[4+m][j] = __builtin_amdgcn_mfma_f32_16x16x32_bf16(a4[m], b4[j], acc[4+m][j], 0, 0, 0);
    __builtin_amdgcn_s_setprio(0);
    BAR();
  }

  // ---- epilogue: gate + store + fused per-chunk affine composition ----
  // C_cat col = by*256 + wc*64 + j*16 + lr; pair (j=2u, 2u+1) = (pz, ph) for
  // d = (by*8 + wc*2 + u)*16 + lr. Rows: bx*256 + wr*128 + m*16 + q*4 + r;
  // CH=16 -> each m-frag is one chunk.
  const int rowb = bx*256 + wr*128;
  #pragma unroll
  for (int u = 0; u < 2; ++u) {
    const int e = (by*8 + wc*2 + u)*16 + lr;
    const float bzv = bz[e];
    const float bhv = bh[e];
    float Aseg[8], Bseg[8];
    #pragma unroll
    for (int m = 0; m < 8; ++m) {
      const int mbase = rowb + m*16 + q*4;
      float A = 1.0f, Bv = 0.0f;
      #pragma unroll
      for (int r = 0; r < 4; ++r) {
        const size_t idx = (size_t)(mbase + r)*DSZ + e;
        const float pz = acc[m][2*u][r]   + bzv;
        const float ph = acc[m][2*u+1][r] + bhv;
        const float ex = __expf(-pz);
        const float z  = 1.0f / (1.0f + ex);
        const __bf16 abf = (__bf16)fmaf(ex, z, 1e-8f);  // (1-z) + 1e-8
        const float  af  = (float)abf;                   // rounded, matches pass3
        const float  bf  = z * ph;
        a_ws[idx]  = abf;
        b_out[idx] = bf;
        Bv = fmaf(af, Bv, bf);
        A *= af;
      }
      Aseg[m] = A; Bseg[m] = Bv;
    }
    // q-lane scan (stride 16): q=3 ends with the full 16-row chunk aggregate.
    #pragma unroll
    for (int m = 0; m < 8; ++m) {
      #pragma unroll
      for (int s = 16; s < 64; s <<= 1) {
        const float Ap = __shfl_up(Aseg[m], s, 64);
        const float Bp = __shfl_up(Bseg[m], s, 64);
        if (lane >= s) { Bseg[m] = fmaf(Aseg[m], Bp, Bseg[m]); Aseg[m] *= Ap; }
      }
    }
    if (q == 3) {
      #pragma unroll
      for (int m = 0; m < 8; ++m) {
        const int bc = (rowb + m*16) >> 4;    // = b*NC + chunk (NC=256)
        Aprod[(size_t)bc*DSZ + e] = Aseg[m];
        Bcomp[(size_t)bc*DSZ + e] = Bseg[m];
      }
    }
  }
}

// ---------------- scan pass 2: lane = d (coalesced), serial over chunks ------
// One wave per (b, 64-d slice): 64 waves. 16-deep register batching; all
// accesses 256B wave-coalesced. Hstart aliases Aprod (reads of a batch issue
// before that batch's stores; disjoint cells per thread) -- no __restrict__.
#define P2B 16
__global__ void scan_pass2_kernel(const float* Aprod,
                                  const float* __restrict__ Bcomp,
                                  float* Hstart)
{
  const int lane = threadIdx.x & 63;
  const int b    = blockIdx.x >> 4;
  const int d    = (blockIdx.x & 15) * 64 + lane;
  const size_t base = (size_t)b * NC * DSZ + d;
  float h = 0.0f;
  for (int c0 = 0; c0 < NC; c0 += P2B) {
    float Ar[P2B], Br[P2B];
    #pragma unroll
    for (int c = 0; c < P2B; ++c) {
      Ar[c] = Aprod[base + (size_t)(c0 + c)*DSZ];
      Br[c] = Bcomp[base + (size_t)(c0 + c)*DSZ];
    }
    #pragma unroll
    for (int c = 0; c < P2B; ++c) {
      Hstart[base + (size_t)(c0 + c)*DSZ] = h;
      h = fmaf(Ar[c], h, Br[c]);
    }
  }
}

// ---------------- scan pass 3: apply within chunk (4 d per thread) -----------
__global__ void scan_pass3_kernel(const __bf16* __restrict__ a_ws,
                                  const float* __restrict__ Hstart,
                                  float* __restrict__ out)
{
  const int bc   = blockIdx.x;               // 0..BSZ*NC-1
  const int d0   = threadIdx.x * 4;
  const size_t base = (size_t)bc * CH * DSZ + d0;
  float4 hv = *(const float4*)(Hstart + (size_t)bc*DSZ + d0);
  float h[4] = {hv.x, hv.y, hv.z, hv.w};
  #pragma unroll
  for (int t = 0; t < CH; ++t) {
    bf16x4 a4 = *(const bf16x4*)(a_ws + base + (size_t)t*DSZ);
    float4 b4 = *(const float4*)(out + base + (size_t)t*DSZ);
    const float bb[4] = {b4.x, b4.y, b4.z, b4.w};
    #pragma unroll
    for (int c = 0; c < 4; ++c)
      h[c] = fmaf((float)a4[c], h[c], bb[c]);
    *(float4*)(out + base + (size_t)t*DSZ) = make_float4(h[0], h[1], h[2], h[3]);
  }
}

extern "C" void kernel_launch(void* const* d_in, const int* in_sizes, int n_in,
                              void* d_out, int out_size, void* d_ws, size_t ws_size,
                              hipStream_t stream)
{
  const float* x  = (const float*)d_in[0];
  const float* Wz = (const float*)d_in[1];
  const float* bz = (const float*)d_in[2];
  const float* Wh = (const float*)d_in[3];
  const float* bh = (const float*)d_in[4];
  float* out = (float*)d_out;

  // ws: Xc (32MB) | Wc (4MB) | a (32MB) | Aprod (4MB) | Bcomp (4MB)
  __bf16* Xc   = (__bf16*)d_ws;
  __bf16* Wc   = Xc + (size_t)MSZ * DSZ;
  __bf16* a_ws = Wc + (size_t)NSZ * DSZ;
  float* Aprod  = (float*)(a_ws + (size_t)MSZ * DSZ);
  float* Bcomp  = Aprod + (size_t)BSZ*NC*DSZ;
  float* Hstart = Aprod;   // alias

  convert_tile_kernel<<<9216, 256, 0, stream>>>(x, Wz, Wh, Xc, Wc);
  gemm_gate_kernel<<<512, 512, 0, stream>>>(Xc, Wc, bz, bh, a_ws, out, Aprod, Bcomp);
  scan_pass2_kernel<<<64, 64, 0, stream>>>(Aprod, Bcomp, Hstart);
  scan_pass3_kernel<<<BSZ*NC, 256, 0, stream>>>(a_ws, Hstart, out);
}

// Round 5
// 243.677 us; speedup vs baseline: 1.0286x; 1.0286x over previous
//
#include <hip/hip_runtime.h>
#include <hip/hip_bf16.h>

// MinGRU forward: z=sigmoid(xWz^T), h~=xWh^T, a=1-z+1e-8, b=z*h~, scan h=a*h+b.
// B=4 T=4096 D=1024.
// R8: (1) gemm REVERTED to the best-measured structure (R5: dual-accumulate
// 128x128 tile, BK=64, MfmaUtil ~31) -- the 4-phase 256^2 counted-vmcnt
// rewrites (R6/R7) both measured MfmaUtil 28 and are abandoned. (2) The gemm
// epilogue now stores WITHIN-CHUNK PREFIXES (Apre,Bpre) instead of raw (a,b):
// h_t = Apre_t*Hstart[chunk] + Bpre_t. Same bytes, but pass3 loses its 16-step
// dependent chain and becomes pure streaming elementwise fma (it was the
// largest tail slack: 164MB that should take ~26us BW-bound but ran ~40-50us
// chained). pass2 unchanged (chunk aggregates identical). Numerics: prefixes
// built from the same bf16-rounded a in f32 + one extra bf16 rounding.

typedef __bf16 bf16x8 __attribute__((ext_vector_type(8)));
typedef __bf16 bf16x4 __attribute__((ext_vector_type(4)));
typedef float  f32x4  __attribute__((ext_vector_type(4)));

#define BSZ 4
#define TSZ 4096
#define DSZ 1024
#define MSZ (BSZ*TSZ)      // 16384 rows
#define CH  16             // scan chunk length
#define NC  (TSZ/CH)       // 256 chunks per sequence

__device__ __forceinline__ void gload_lds16(const __bf16* g, __bf16* l) {
  __builtin_amdgcn_global_load_lds(
      (const __attribute__((address_space(1))) void*)g,
      (__attribute__((address_space(3))) void*)l, 16, 0, 0);
}

// ---------------- conversion: fp32 row-major -> bf16 fragment-tiled ----------------
// tiled layout: [rowblk][kblk:32][i:8][l:64][j:8] where
//   row = rowblk*128 + i*16 + (l&15), k = kblk*32 + (l>>4)*8 + j
__global__ void convert_tile_kernel(const float* __restrict__ X,
                                    const float* __restrict__ Wz,
                                    const float* __restrict__ Wh,
                                    __bf16* __restrict__ Xc,
                                    __bf16* __restrict__ Wzc,
                                    __bf16* __restrict__ Whc)
{
  const int bx = blockIdx.x;
  const float* src; __bf16* dst; int gid;
  if (bx < 8192)      { src = X;  dst = Xc;  gid =  bx        *256 + threadIdx.x; }
  else if (bx < 8704) { src = Wz; dst = Wzc; gid = (bx - 8192)*256 + threadIdx.x; }
  else                { src = Wh; dst = Whc; gid = (bx - 8704)*256 + threadIdx.x; }
  const int l    = gid & 63;
  const int i    = (gid >> 6) & 7;
  const int kblk = (gid >> 9) & 31;
  const int rblk = gid >> 14;
  const int row  = rblk*128 + i*16 + (l & 15);
  const int col  = kblk*32 + (l >> 4)*8;
  const float* g = src + (size_t)row*DSZ + col;
  float4 v0 = *(const float4*)g;
  float4 v1 = *(const float4*)(g + 4);
  bf16x8 p;
  p[0]=(__bf16)v0.x; p[1]=(__bf16)v0.y; p[2]=(__bf16)v0.z; p[3]=(__bf16)v0.w;
  p[4]=(__bf16)v1.x; p[5]=(__bf16)v1.y; p[6]=(__bf16)v1.z; p[7]=(__bf16)v1.w;
  *(bf16x8*)(dst + (size_t)gid*8) = p;
}

// ---------------- GEMM + gate epilogue + fused per-chunk prefix/composition ----
// block tile 128(M) x 128(N), BK=64; 256 threads = 4 waves in 2x2, each wave 64x64.
__global__ __launch_bounds__(256, 2) void gemm_gate_kernel(
    const __bf16* __restrict__ Xc,  const __bf16* __restrict__ Wzc,
    const __bf16* __restrict__ Whc,
    const float* __restrict__ bz, const float* __restrict__ bh,
    __bf16* __restrict__ a_ws, float* __restrict__ b_out,
    float* __restrict__ Aprod, float* __restrict__ Bcomp)
{
  __shared__ __align__(16) __bf16 As [8192];
  __shared__ __align__(16) __bf16 Bzs[8192];
  __shared__ __align__(16) __bf16 Bhs[8192];

  const int tid  = threadIdx.x;
  const int lane = tid & 63;
  const int wv   = tid >> 6;
  const int wM   = (wv >> 1) * 64;
  const int wN   = (wv & 1) * 64;
  const int wMg  = wM >> 4;
  const int wNg  = wN >> 4;
  const int lr   = lane & 15;
  const int q    = lane >> 4;
  const int wbase = wv * 64;           // wave-uniform

  const __bf16* Xb = Xc  + (size_t)blockIdx.x * 32 * 4096;
  const __bf16* Zb = Wzc + (size_t)blockIdx.y * 32 * 4096;
  const __bf16* Hb = Whc + (size_t)blockIdx.y * 32 * 4096;

  f32x4 accz[4][4] = {};
  f32x4 acch[4][4] = {};

  for (int kblk = 0; kblk < 16; ++kblk) {   // BK=64: two 32-wide k-slices per iter
    __syncthreads();
    const size_t tb = (size_t)kblk * 8192;
    #pragma unroll
    for (int c = 0; c < 4; ++c) {
      const int eo = (c*256 + wbase + lane) * 8;  // per-lane global elem offset
      const int lo = (c*256 + wbase) * 8;         // wave-uniform LDS elem offset
      gload_lds16(Xb + tb + eo, As  + lo);
      gload_lds16(Zb + tb + eo, Bzs + lo);
      gload_lds16(Hb + tb + eo, Bhs + lo);
    }
    __syncthreads();

    #pragma unroll
    for (int h = 0; h < 2; ++h) {
      const int ho = h * 4096;                    // select k-slice within LDS
      bf16x8 af[4];
      #pragma unroll
      for (int i = 0; i < 4; ++i)
        af[i] = *(const bf16x8*)(As + ho + (wMg + i)*512 + lane*8);
      #pragma unroll
      for (int j = 0; j < 4; ++j) {
        bf16x8 bz8 = *(const bf16x8*)(Bzs + ho + (wNg + j)*512 + lane*8);
        bf16x8 bh8 = *(const bf16x8*)(Bhs + ho + (wNg + j)*512 + lane*8);
        #pragma unroll
        for (int i = 0; i < 4; ++i) {
          accz[j][i] = __builtin_amdgcn_mfma_f32_16x16x32_bf16(af[i], bz8, accz[j][i], 0, 0, 0);
          acch[j][i] = __builtin_amdgcn_mfma_f32_16x16x32_bf16(af[i], bh8, acch[j][i], 0, 0, 0);
        }
      }
    }
  }

  // ---- epilogue: gate + within-chunk prefix + chunk aggregate ----
  // C/D layout col=lane&15, row=(lane>>4)*4+reg (verified m89/m91).
  // CH=16 -> each i-fragment (rows mbase..mbase+15 over q,r) is one chunk.
  // Per lane: running prefix (Ar[r],Br[r]) over its 4 rows; inclusive q-scan
  // gives segment aggregates; exclusive q-prefix (EA,EB) composes to the
  // per-row within-chunk prefix: Apre = Ar*EA, Bpre = Ar*EB + Br, so that
  // h_row = Apre*Hstart[chunk] + Bpre  (pass3 is then chain-free).
  const int M0 = blockIdx.x * 128;
  const int N0 = blockIdx.y * 128;
  #pragma unroll
  for (int j = 0; j < 4; ++j) {
    const int e = N0 + wN + j*16 + lr;
    const float bzv = bz[e];
    const float bhv = bh[e];
    #pragma unroll
    for (int i = 0; i < 4; ++i) {
      const int mbase = M0 + wM + i*16 + q*4;
      float Ar[4], Br[4];
      float A = 1.0f, Bv = 0.0f;
      #pragma unroll
      for (int r = 0; r < 4; ++r) {
        const float pz = accz[j][i][r] + bzv;
        const float ph = acch[j][i][r] + bhv;
        const float ex = __expf(-pz);
        const float z  = 1.0f / (1.0f + ex);
        const float af = (float)(__bf16)fmaf(ex, z, 1e-8f);  // bf16-rounded (1-z)+1e-8
        const float bf = z * ph;
        Bv = fmaf(af, Bv, bf);
        A *= af;
        Ar[r] = A; Br[r] = Bv;
      }
      // inclusive scan across the 4 q-lane groups (stride 16)
      float sA = A, sB = Bv;
      #pragma unroll
      for (int s = 16; s < 64; s <<= 1) {
        const float Ap = __shfl_up(sA, s, 64);
        const float Bp = __shfl_up(sB, s, 64);
        if (lane >= s) { sB = fmaf(sA, Bp, sB); sA *= Ap; }
      }
      // exclusive prefix for this q-group (identity at q==0)
      float EA = __shfl_up(sA, 16, 64);
      float EB = __shfl_up(sB, 16, 64);
      if (q == 0) { EA = 1.0f; EB = 0.0f; }
      #pragma unroll
      for (int r = 0; r < 4; ++r) {
        const size_t idx = (size_t)(mbase + r)*DSZ + e;
        const float Apre = Ar[r] * EA;
        const float Bpre = fmaf(Ar[r], EB, Br[r]);
        a_ws[idx]  = (__bf16)Apre;
        b_out[idx] = Bpre;
      }
      if (q == 3) {   // full 16-row chunk aggregate
        const int bc = (M0 + wM + i*16) >> 4;   // = b*NC + chunk (NC=256)
        Aprod[(size_t)bc*DSZ + e] = sA;
        Bcomp[(size_t)bc*DSZ + e] = sB;
      }
    }
  }
}

// ---------------- scan pass 2: lane = d (coalesced), serial over chunks ------
// One wave per (b, 64-d slice): 64 waves. 16-deep register batching; all
// accesses 256B wave-coalesced. Hstart aliases Aprod (reads of a batch issue
// before that batch's stores; disjoint cells per thread) -- no __restrict__.
#define P2B 16
__global__ void scan_pass2_kernel(const float* Aprod,
                                  const float* __restrict__ Bcomp,
                                  float* Hstart)
{
  const int lane = threadIdx.x & 63;
  const int b    = blockIdx.x >> 4;
  const int d    = (blockIdx.x & 15) * 64 + lane;
  const size_t base = (size_t)b * NC * DSZ + d;
  float h = 0.0f;
  for (int c0 = 0; c0 < NC; c0 += P2B) {
    float Ar[P2B], Br[P2B];
    #pragma unroll
    for (int c = 0; c < P2B; ++c) {
      Ar[c] = Aprod[base + (size_t)(c0 + c)*DSZ];
      Br[c] = Bcomp[base + (size_t)(c0 + c)*DSZ];
    }
    #pragma unroll
    for (int c = 0; c < P2B; ++c) {
      Hstart[base + (size_t)(c0 + c)*DSZ] = h;
      h = fmaf(Ar[c], h, Br[c]);
    }
  }
}

// ---------------- scan pass 3: chain-free apply, out = Apre*H0 + Bpre --------
// All 16 t-iterations independent (no carried h) -> pure streaming fma at
// full memory-level parallelism. 1024 blocks x 256 thr, 4 d per thread.
__global__ void scan_pass3_kernel(const __bf16* __restrict__ a_ws,
                                  const float* __restrict__ Hstart,
                                  float* __restrict__ out)
{
  const int bc   = blockIdx.x;               // 0..BSZ*NC-1
  const int d0   = threadIdx.x * 4;
  const size_t base = (size_t)bc * CH * DSZ + d0;
  const float4 hv = *(const float4*)(Hstart + (size_t)bc*DSZ + d0);
  const float h0[4] = {hv.x, hv.y, hv.z, hv.w};
  #pragma unroll
  for (int t = 0; t < CH; ++t) {
    bf16x4 a4 = *(const bf16x4*)(a_ws + base + (size_t)t*DSZ);
    float4 b4 = *(const float4*)(out + base + (size_t)t*DSZ);
    float o[4] = {b4.x, b4.y, b4.z, b4.w};
    #pragma unroll
    for (int c = 0; c < 4; ++c)
      o[c] = fmaf((float)a4[c], h0[c], o[c]);
    *(float4*)(out + base + (size_t)t*DSZ) = make_float4(o[0], o[1], o[2], o[3]);
  }
}

extern "C" void kernel_launch(void* const* d_in, const int* in_sizes, int n_in,
                              void* d_out, int out_size, void* d_ws, size_t ws_size,
                              hipStream_t stream)
{
  const float* x  = (const float*)d_in[0];
  const float* Wz = (const float*)d_in[1];
  const float* bz = (const float*)d_in[2];
  const float* Wh = (const float*)d_in[3];
  const float* bh = (const float*)d_in[4];
  float* out = (float*)d_out;

  // ws layout: Xc (32MB) | Wzc (2MB) | Whc (2MB) | a (32MB) | Aprod (4MB) | Bcomp (4MB)
  // Hstart aliases Aprod (pass2 reads each cell before overwriting it).
  __bf16* Xc   = (__bf16*)d_ws;
  __bf16* Wzc  = Xc  + (size_t)MSZ * DSZ;
  __bf16* Whc  = Wzc + (size_t)DSZ * DSZ;
  __bf16* a_ws = Whc + (size_t)DSZ * DSZ;
  float* Aprod  = (float*)(a_ws + (size_t)MSZ * DSZ);
  float* Bcomp  = Aprod + (size_t)BSZ*NC*DSZ;
  float* Hstart = Aprod;   // alias

  convert_tile_kernel<<<9216, 256, 0, stream>>>(x, Wz, Wh, Xc, Wzc, Whc);
  gemm_gate_kernel<<<dim3(MSZ/128, DSZ/128), 256, 0, stream>>>(
      Xc, Wzc, Whc, bz, bh, a_ws, out, Aprod, Bcomp);
  scan_pass2_kernel<<<64, 64, 0, stream>>>(Aprod, Bcomp, Hstart);
  scan_pass3_kernel<<<BSZ*NC, 256, 0, stream>>>(a_ws, Hstart, out);
}